// Round 1
// 770.494 us; speedup vs baseline: 1.0248x; 1.0248x over previous
//
#include <hip/hip_runtime.h>

typedef unsigned short u16;
typedef unsigned int u32;
typedef __attribute__((ext_vector_type(8))) short short8;
typedef __attribute__((ext_vector_type(4))) float f32x4;

#define DIMC 768
#define NQKV 2304
#define NPOS 32768
#define NKT 12   // 768 / 64

__device__ __forceinline__ float b2f(u16 u) {
    union { u32 i; float f; } c; c.i = ((u32)u) << 16; return c.f;
}
__device__ __forceinline__ u16 f2b(float f) {
    union { float f; u32 i; } c; c.f = f;
    u32 r = c.i + 0x7fffu + ((c.i >> 16) & 1u);
    return (u16)(r >> 16);
}

// async global->LDS, 16B per lane; lds dst is wave-uniform base + lane*16
__device__ __forceinline__ void gl_lds16(const void* g, void* l) {
    __builtin_amdgcn_global_load_lds(
        (const __attribute__((address_space(1))) void*)g,
        (__attribute__((address_space(3))) void*)l, 16, 0, 0);
}

// ---- fp32 -> bf16 elementwise (x) ----
__global__ __launch_bounds__(256) void cvt_bf16(
    const float* __restrict__ in, u16* __restrict__ out, int n4)
{
    int i = blockIdx.x * 256 + threadIdx.x;
    if (i >= n4) return;
    float4 v = ((const float4*)in)[i];
    ushort4 o;
    o.x = f2b(v.x); o.y = f2b(v.y); o.z = f2b(v.z); o.w = f2b(v.w);
    ((ushort4*)out)[i] = o;
}

// ---- fp32 W[768][N] -> bf16 WT[N][768] (transpose + convert), 64x64 tiles ----
__global__ __launch_bounds__(256) void cvt_wT(
    const float* __restrict__ W0, const float* __restrict__ W1,
    const float* __restrict__ W2,
    u16* __restrict__ T0, u16* __restrict__ T1, u16* __restrict__ T2)
{
    const int z = blockIdx.z;
    const float* W = (z == 0) ? W0 : (z == 1) ? W1 : W2;
    u16* WT = (z == 0) ? T0 : (z == 1) ? T1 : T2;
    const int N = (z == 2) ? 768 : 2304;
    const int nb = blockIdx.x, kb = blockIdx.y;
    if (nb * 64 >= N) return;                       // block-uniform
    __shared__ u16 T[64][65];
    const int t = threadIdx.x, sr = t >> 2, sc = t & 3;
    {
        const float4* p = (const float4*)(W + (size_t)(kb * 64 + sr) * N + nb * 64 + sc * 16);
        float4 a0 = p[0], a1 = p[1], a2 = p[2], a3 = p[3];
        float vv[16] = {a0.x, a0.y, a0.z, a0.w, a1.x, a1.y, a1.z, a1.w,
                        a2.x, a2.y, a2.z, a2.w, a3.x, a3.y, a3.z, a3.w};
        #pragma unroll
        for (int i = 0; i < 16; ++i)
            T[sc * 16 + i][sr] = f2b(vv[i]);
    }
    __syncthreads();
    {
        u16 vv[16];
        #pragma unroll
        for (int i = 0; i < 16; ++i) vv[i] = T[sr][sc * 16 + i];
        uint4 p0, p1;
        p0.x = vv[0] | ((u32)vv[1] << 16);  p0.y = vv[2] | ((u32)vv[3] << 16);
        p0.z = vv[4] | ((u32)vv[5] << 16);  p0.w = vv[6] | ((u32)vv[7] << 16);
        p1.x = vv[8] | ((u32)vv[9] << 16);  p1.y = vv[10] | ((u32)vv[11] << 16);
        p1.z = vv[12] | ((u32)vv[13] << 16); p1.w = vv[14] | ((u32)vv[15] << 16);
        u16* q = WT + (size_t)(nb * 64 + sr) * DIMC + kb * 64 + sc * 16;
        *(uint4*)q = p0;
        *(uint4*)(q + 8) = p1;
    }
}

// ============================================================================
// 256x256 8-phase MFMA GEMM (T1 XCD-swizzle + T2 LDS XOR-swizzle + T3/T4
// counted-vmcnt phase pipeline + T5 setprio). C[M][ldn] = A[M][768] @ BT^T + b.
// 512 threads = 8 waves (2M x 4N); each wave owns 128x64 output; BK=64.
// LDS: 2 x [256][64] bf16 per matrix = 128 KiB, 1 block/CU, 2 waves/SIMD.
//
// LDS swizzle: LDS[row][chunk c] (16B chunks) holds global chunk c^(row&7).
// global_load_lds writes linearly, so the SOURCE address is pre-swizzled
// (same involution) and ds_reads apply the XOR on the read side.
//
// Per K-tile t (buffer p=t&1), 4 phases, quadrant order (hm,hn)=(0,0),(0,1),
// (1,0),(1,1); stages: ph1: t+1 A-ht1 -> buf q; ph2: t+1 B-ht1 -> buf q;
// ph3: t+2 B-ht0 -> buf p (B[p] reads finished ph2); ph4: t+2 A-ht0 -> buf p
// (A[p] reads finished ph3). Boundary: s_waitcnt vmcnt(4) (the 4 newest loads
// are t+2's ph3/ph4 stages; everything needed for t+1 is older) + s_barrier.
// Tail: t=NKT-2 stages only t+1 (vmcnt 0); t=NKT-1 stages nothing.
// ============================================================================

#define STAGE_A(buf, kt, ht) do {                                              \
    gl_lds16(aS + (size_t)((ht) * 128)      * DIMC + (size_t)(kt) * 64,        \
             &As[buf][(ht) * 8192 +        w * 512]);                          \
    gl_lds16(aS + (size_t)((ht) * 128 + 64) * DIMC + (size_t)(kt) * 64,        \
             &As[buf][(ht) * 8192 + 4096 + w * 512]);                          \
} while (0)

#define STAGE_B(buf, kt, ht) do {                                              \
    gl_lds16(bS + (size_t)((ht) * 128)      * DIMC + (size_t)(kt) * 64,        \
             &Bs[buf][(ht) * 8192 +        w * 512]);                          \
    gl_lds16(bS + (size_t)((ht) * 128 + 64) * DIMC + (size_t)(kt) * 64,        \
             &Bs[buf][(ht) * 8192 + 4096 + w * 512]);                          \
} while (0)

#define LOAD_A(hm) do {                                                        \
    _Pragma("unroll")                                                          \
    for (int i_ = 0; i_ < 4; ++i_) {                                           \
        const int row_ = wm * 128 + (hm) * 64 + i_ * 16 + lr;                  \
        _Pragma("unroll")                                                      \
        for (int ks_ = 0; ks_ < 2; ++ks_)                                      \
            af[i_][ks_] = *(const short8*)(Ab_ + (row_ << 6) +                 \
                              (((ks_ * 4 + lq) ^ (row_ & 7)) << 3));           \
    }                                                                          \
} while (0)

#define LOAD_B(dst, hn) do {                                                   \
    _Pragma("unroll")                                                          \
    for (int j_ = 0; j_ < 2; ++j_) {                                           \
        const int row_ = wn * 64 + (hn) * 32 + j_ * 16 + lr;                   \
        _Pragma("unroll")                                                      \
        for (int ks_ = 0; ks_ < 2; ++ks_)                                      \
            dst[j_][ks_] = *(const short8*)(Bb_ + (row_ << 6) +                \
                              (((ks_ * 4 + lq) ^ (row_ & 7)) << 3));           \
    }                                                                          \
} while (0)

#define MM(hm, hn, bsrc) do {                                                  \
    __builtin_amdgcn_s_setprio(1);                                             \
    _Pragma("unroll")                                                          \
    for (int i_ = 0; i_ < 4; ++i_)                                             \
        _Pragma("unroll")                                                      \
        for (int j_ = 0; j_ < 2; ++j_)                                         \
            _Pragma("unroll")                                                  \
            for (int ks_ = 0; ks_ < 2; ++ks_)                                  \
                acc[(hm) * 4 + i_][(hn) * 2 + j_] =                            \
                    __builtin_amdgcn_mfma_f32_16x16x32_bf16(                   \
                        af[i_][ks_], bsrc[j_][ks_],                            \
                        acc[(hm) * 4 + i_][(hn) * 2 + j_], 0, 0, 0);           \
    __builtin_amdgcn_s_setprio(0);                                             \
} while (0)

#define PBAR() do {                                                            \
    __builtin_amdgcn_sched_barrier(0);                                         \
    __builtin_amdgcn_s_barrier();                                              \
    __builtin_amdgcn_sched_barrier(0);                                         \
} while (0)

#define KTILE_BODY(kt, S1, S2, VN) do {                                        \
    const int p_ = (kt) & 1;                                                   \
    const u16* Ab_ = As[p_];                                                   \
    const u16* Bb_ = Bs[p_];                                                   \
    /* phase 1: quad (0,0) */                                                  \
    LOAD_A(0);                                                                 \
    LOAD_B(b0f, 0);                                                            \
    if (S1) STAGE_A(p_ ^ 1, (kt) + 1, 1);                                      \
    PBAR();                                                                    \
    MM(0, 0, b0f);                                                             \
    PBAR();                                                                    \
    /* phase 2: quad (0,1) */                                                  \
    LOAD_B(b1f, 1);                                                            \
    if (S1) STAGE_B(p_ ^ 1, (kt) + 1, 1);                                      \
    PBAR();                                                                    \
    MM(0, 1, b1f);                                                             \
    PBAR();                                                                    \
    /* phase 3: quad (1,0) */                                                  \
    LOAD_A(1);                                                                 \
    if (S2) STAGE_B(p_, (kt) + 2, 0);                                          \
    PBAR();                                                                    \
    MM(1, 0, b0f);                                                             \
    PBAR();                                                                    \
    /* phase 4: quad (1,1) */                                                  \
    if (S2) STAGE_A(p_, (kt) + 2, 0);                                          \
    PBAR();                                                                    \
    MM(1, 1, b1f);                                                             \
    /* K-tile boundary: counted vmcnt, never drain in steady state */          \
    __builtin_amdgcn_sched_barrier(0);                                         \
    asm volatile("s_waitcnt vmcnt(" VN ")" ::: "memory");                      \
    __builtin_amdgcn_s_barrier();                                              \
    __builtin_amdgcn_sched_barrier(0);                                         \
} while (0)

__global__ __launch_bounds__(512, 2) void gemm256(
    const u16* __restrict__ A, const u16* __restrict__ BT,
    const float* __restrict__ bias, void* __restrict__ C,
    int ldn, int c_is_f32)
{
    __shared__ __align__(16) u16 As[2][256 * 64];   // 64 KiB
    __shared__ __align__(16) u16 Bs[2][256 * 64];   // 64 KiB

    const int t = threadIdx.x;
    const int w = t >> 6, l = t & 63;
    const int wm = w >> 2, wn = w & 3;              // 2M x 4N wave grid
    const int lr = l & 15, lq = l >> 4;

    // T1: bijective XCD swizzle (nwg = 1152 or 384, both % 8 == 0)
    const int gx = (int)gridDim.x;
    const int nwg = gx * (int)gridDim.y;
    const int lin = (int)blockIdx.y * gx + (int)blockIdx.x;
    const int swz = (lin & 7) * (nwg >> 3) + (lin >> 3);
    const int by = swz / gx, bx = swz - by * gx;
    const int mBase = by * 256, nBase = bx * 256;

    // staging source (pre-swizzled so linear global_load_lds yields
    // LDS[row][c] = global chunk c^(row&7))
    const int srow = t >> 3;                         // 0..63
    const int schk = (t & 7) ^ (srow & 7);           // swizzled 16B chunk
    const u16* aS = A  + (size_t)(mBase + srow) * DIMC + schk * 8;
    const u16* bS = BT + (size_t)(nBase + srow) * DIMC + schk * 8;

    f32x4 acc[8][4];
    #pragma unroll
    for (int i = 0; i < 8; ++i)
        #pragma unroll
        for (int j = 0; j < 4; ++j)
            acc[i][j] = (f32x4){0.f, 0.f, 0.f, 0.f};

    short8 af[4][2], b0f[2][2], b1f[2][2];

    // prologue: tile0 full (buf0) + tile1 {B-ht0, A-ht0} (buf1); then the
    // 4 newest loads (tile1's) may stay in flight -> vmcnt(4)
    STAGE_A(0, 0, 0); STAGE_A(0, 0, 1);
    STAGE_B(0, 0, 0); STAGE_B(0, 0, 1);
    STAGE_B(1, 1, 0); STAGE_A(1, 1, 0);
    asm volatile("s_waitcnt vmcnt(4)" ::: "memory");
    __builtin_amdgcn_s_barrier();
    __builtin_amdgcn_sched_barrier(0);

    #pragma unroll 1
    for (int kt = 0; kt < NKT - 2; ++kt) { KTILE_BODY(kt, 1, 1, "4"); }
    { KTILE_BODY(NKT - 2, 1, 0, "0"); }
    { KTILE_BODY(NKT - 1, 0, 0, "0"); }

    // epilogue: C/D layout col=lane&15, row=(lane>>4)*4+reg (m89-verified)
    #pragma unroll
    for (int nf = 0; nf < 4; ++nf) {
        const int col = nBase + wn * 64 + nf * 16 + lr;
        const float bb = bias[col];
        #pragma unroll
        for (int mf = 0; mf < 8; ++mf) {
            const int row = mBase + wm * 128 + mf * 16 + lq * 4;
            #pragma unroll
            for (int rg = 0; rg < 4; ++rg) {
                float v = acc[mf][nf][rg] + bb;
                size_t idx = (size_t)(row + rg) * ldn + col;
                if (c_is_f32) ((float*)C)[idx] = v;
                else          ((u16*)C)[idx]   = f2b(v);
            }
        }
    }
}

// ---- head-attention per position (bf16 qkv in, bf16 sum out) ----
__global__ __launch_bounds__(256) void headattn(
    const u16* __restrict__ qkv, u16* __restrict__ sum, int accumulate)
{
    __shared__ float qs[4][12 * 65];
    __shared__ float ks[4][12 * 65];
    __shared__ float vs[4][12 * 65];
    __shared__ float Sld[4][144];
    const int t = threadIdx.x, wv = t >> 6, lane = t & 63;
    const int p = blockIdx.x * 4 + wv;
    const u16* row = qkv + (size_t)p * NQKV;

    #pragma unroll
    for (int j = 0; j < 9; ++j) {
        int u2 = lane + 64 * j;
        uint2 d2 = *(const uint2*)(row + u2 * 4);
        int c = u2 * 4;
        int s = c / 768, rr = c % 768;
        int h = rr >> 6, d = rr & 63;
        float* dst = (s == 0) ? qs[wv] : (s == 1) ? ks[wv] : vs[wv];
        dst[h * 65 + d + 0] = b2f((u16)(d2.x & 0xffffu));
        dst[h * 65 + d + 1] = b2f((u16)(d2.x >> 16));
        dst[h * 65 + d + 2] = b2f((u16)(d2.y & 0xffffu));
        dst[h * 65 + d + 3] = b2f((u16)(d2.y >> 16));
    }
    __syncthreads();
    for (int e = lane; e < 144; e += 64) {
        int h = e / 12, g = e - h * 12;
        float s = 0.f;
        #pragma unroll 8
        for (int d = 0; d < 64; ++d)
            s = fmaf(qs[wv][h * 65 + d], ks[wv][g * 65 + d], s);
        Sld[wv][e] = s * 0.125f;
    }
    __syncthreads();
    if (lane < 12) {
        float m = -1e30f;
        #pragma unroll
        for (int g = 0; g < 12; ++g) m = fmaxf(m, Sld[wv][lane * 12 + g]);
        float ex[12]; float ssum = 0.f;
        #pragma unroll
        for (int g = 0; g < 12; ++g) { ex[g] = __expf(Sld[wv][lane * 12 + g] - m); ssum += ex[g]; }
        float inv = 1.f / ssum;
        #pragma unroll
        for (int g = 0; g < 12; ++g) Sld[wv][lane * 12 + g] = ex[g] * inv;
    }
    __syncthreads();
    u16* orow = sum + (size_t)p * DIMC;
    #pragma unroll
    for (int h = 0; h < 12; ++h) {
        float o = 0.f;
        #pragma unroll
        for (int g = 0; g < 12; ++g)
            o = fmaf(Sld[wv][h * 12 + g], vs[wv][g * 65 + lane], o);
        int idx = h * 64 + lane;
        if (accumulate) o += b2f(orow[idx]);
        orow[idx] = f2b(o);
    }
}

extern "C" void kernel_launch(void* const* d_in, const int* in_sizes, int n_in,
                              void* d_out, int out_size, void* d_ws, size_t ws_size,
                              hipStream_t stream) {
    const float* x  = (const float*)d_in[0];
    const float* wh = (const float*)d_in[1];
    const float* bh = (const float*)d_in[2];
    const float* ww = (const float*)d_in[3];
    const float* bw = (const float*)d_in[4];
    const float* wp = (const float*)d_in[5];
    const float* bp = (const float*)d_in[6];
    float* out = (float*)d_out;

    // ws (u16 elems): xb 25165824 | whT 1769472 | wwT 1769472 | wpT 589824 |
    //                 qkv 75497472 | sumb 25165824   => ~260 MB
    u16* xb   = (u16*)d_ws;
    u16* whT  = xb   + 25165824;
    u16* wwT  = whT  + 1769472;
    u16* wpT  = wwT  + 1769472;
    u16* qkvb = wpT  + 589824;
    u16* sumb = qkvb + 75497472;

    cvt_bf16<<<24576, 256, 0, stream>>>(x, xb, 6291456);
    dim3 wg(36, 12, 3);
    cvt_wT<<<wg, 256, 0, stream>>>(wh, ww, wp, whT, wwT, wpT);

    dim3 gq(NQKV / 256, NPOS / 256);      // (9, 128)  -> 1152 blocks
    dim3 gp(DIMC / 256, NPOS / 256);      // (3, 128)  ->  384 blocks

    gemm256<<<gq, 512, 0, stream>>>(xb, whT, bh, qkvb, NQKV, 0);
    headattn<<<NPOS / 4, 256, 0, stream>>>(qkvb, sumb, 0);
    gemm256<<<gq, 512, 0, stream>>>(xb, wwT, bw, qkvb, NQKV, 0);
    headattn<<<NPOS / 4, 256, 0, stream>>>(qkvb, sumb, 1);
    gemm256<<<gp, 512, 0, stream>>>(sumb, wpT, bp, out, DIMC, 1);
}

// Round 2
// 727.605 us; speedup vs baseline: 1.0852x; 1.0589x over previous
//
#include <hip/hip_runtime.h>

typedef unsigned short u16;
typedef unsigned int u32;
typedef __attribute__((ext_vector_type(8))) short short8;
typedef __attribute__((ext_vector_type(4))) float f32x4;

#define DIMC 768
#define NQKV 2304
#define NPOS 32768
#define NKT 12   // 768 / 64

__device__ __forceinline__ float b2f(u16 u) {
    union { u32 i; float f; } c; c.i = ((u32)u) << 16; return c.f;
}
__device__ __forceinline__ u16 f2b(float f) {
    union { float f; u32 i; } c; c.f = f;
    u32 r = c.i + 0x7fffu + ((c.i >> 16) & 1u);
    return (u16)(r >> 16);
}

// async global->LDS, 16B per lane; lds dst is wave-uniform base + lane*16
__device__ __forceinline__ void gl_lds16(const void* g, void* l) {
    __builtin_amdgcn_global_load_lds(
        (const __attribute__((address_space(1))) void*)g,
        (__attribute__((address_space(3))) void*)l, 16, 0, 0);
}

// ---- fp32 -> bf16 elementwise (x) ----
__global__ __launch_bounds__(256) void cvt_bf16(
    const float* __restrict__ in, u16* __restrict__ out, int n4)
{
    int i = blockIdx.x * 256 + threadIdx.x;
    if (i >= n4) return;
    float4 v = ((const float4*)in)[i];
    ushort4 o;
    o.x = f2b(v.x); o.y = f2b(v.y); o.z = f2b(v.z); o.w = f2b(v.w);
    ((ushort4*)out)[i] = o;
}

// ---- fp32 W[768][N] -> bf16 WT[N][768] (transpose + convert), 64x64 tiles ----
__global__ __launch_bounds__(256) void cvt_wT(
    const float* __restrict__ W0, const float* __restrict__ W1,
    const float* __restrict__ W2,
    u16* __restrict__ T0, u16* __restrict__ T1, u16* __restrict__ T2)
{
    const int z = blockIdx.z;
    const float* W = (z == 0) ? W0 : (z == 1) ? W1 : W2;
    u16* WT = (z == 0) ? T0 : (z == 1) ? T1 : T2;
    const int N = (z == 2) ? 768 : 2304;
    const int nb = blockIdx.x, kb = blockIdx.y;
    if (nb * 64 >= N) return;                       // block-uniform
    __shared__ u16 T[64][65];
    const int t = threadIdx.x, sr = t >> 2, sc = t & 3;
    {
        const float4* p = (const float4*)(W + (size_t)(kb * 64 + sr) * N + nb * 64 + sc * 16);
        float4 a0 = p[0], a1 = p[1], a2 = p[2], a3 = p[3];
        float vv[16] = {a0.x, a0.y, a0.z, a0.w, a1.x, a1.y, a1.z, a1.w,
                        a2.x, a2.y, a2.z, a2.w, a3.x, a3.y, a3.z, a3.w};
        #pragma unroll
        for (int i = 0; i < 16; ++i)
            T[sc * 16 + i][sr] = f2b(vv[i]);
    }
    __syncthreads();
    {
        u16 vv[16];
        #pragma unroll
        for (int i = 0; i < 16; ++i) vv[i] = T[sr][sc * 16 + i];
        uint4 p0, p1;
        p0.x = vv[0] | ((u32)vv[1] << 16);  p0.y = vv[2] | ((u32)vv[3] << 16);
        p0.z = vv[4] | ((u32)vv[5] << 16);  p0.w = vv[6] | ((u32)vv[7] << 16);
        p1.x = vv[8] | ((u32)vv[9] << 16);  p1.y = vv[10] | ((u32)vv[11] << 16);
        p1.z = vv[12] | ((u32)vv[13] << 16); p1.w = vv[14] | ((u32)vv[15] << 16);
        u16* q = WT + (size_t)(nb * 64 + sr) * DIMC + kb * 64 + sc * 16;
        *(uint4*)q = p0;
        *(uint4*)(q + 8) = p1;
    }
}

// ============================================================================
// 256x256 MFMA GEMM, 4-barrier/K-tile pipelined schedule.
// 512 threads = 8 waves (2M x 4N); wave output = two 64-row strips (hm half)
// x two 32-col strips (hn half); BK=64; LDS 128 KiB (2 dbuf x [256][64] x A,B).
//
// LDS swizzle (T2): LDS[row][chunk c] holds global chunk c^(row&7); source is
// pre-swizzled for linear global_load_lds, reads XOR on the read side.
//
// Staging: 1 tile ahead into buf q (never read during tile t -> no overwrite
// hazard). Regions == read quadrants exactly:
//   ph1 stages A-lo,B-lo(t+1); ph2 stages B-hi,A-hi(t+1).
// Register prefetch (1 phase ahead; af array reused when dead -> no extra
// VGPRs): ph1 reads af0(8)+b1(4); ph2 (post-MM) reads a1(8); ph4 reads b0'(4).
// Sound cross-wave drain guards ([own vmcnt] -> barrier -> reads):
//   ph3: vmcnt(4) drains ph1's 4 stages -> guards ph4's b0' read.
//   ph4: vmcnt(0) drains ph2's 4 stages (2 phases old, ~free) -> guards
//        next tile's ph1 af0/b1 reads and ph2 a1 read.
// ============================================================================

#define STAGE_A(buf, kt, ht) do {                                              \
    gl_lds16(aS + (size_t)((ht) * 128)      * DIMC + (size_t)(kt) * 64,        \
             &As[buf][(ht) * 8192 +        w * 512]);                          \
    gl_lds16(aS + (size_t)((ht) * 128 + 64) * DIMC + (size_t)(kt) * 64,        \
             &As[buf][(ht) * 8192 + 4096 + w * 512]);                          \
} while (0)

#define STAGE_B(buf, kt, ht) do {                                              \
    gl_lds16(bS + (size_t)((ht) * 128)      * DIMC + (size_t)(kt) * 64,        \
             &Bs[buf][(ht) * 8192 +        w * 512]);                          \
    gl_lds16(bS + (size_t)((ht) * 128 + 64) * DIMC + (size_t)(kt) * 64,        \
             &Bs[buf][(ht) * 8192 + 4096 + w * 512]);                          \
} while (0)

// read A half hm (rows hm*128 + wm*64 + i*16 + lr) into af
#define READ_A(base, hm) do {                                                  \
    _Pragma("unroll")                                                          \
    for (int i_ = 0; i_ < 4; ++i_) {                                           \
        const int row_ = (hm) * 128 + wm * 64 + i_ * 16 + lr;                  \
        _Pragma("unroll")                                                      \
        for (int ks_ = 0; ks_ < 2; ++ks_)                                      \
            af[i_][ks_] = *(const short8*)((base) + (row_ << 6) +              \
                              (((ks_ * 4 + lq) ^ (row_ & 7)) << 3));           \
    }                                                                          \
} while (0)

// read B half hn (rows hn*128 + wn*32 + j*16 + lr) into dst
#define READ_B(dst, base, hn) do {                                             \
    _Pragma("unroll")                                                          \
    for (int j_ = 0; j_ < 2; ++j_) {                                           \
        const int row_ = (hn) * 128 + wn * 32 + j_ * 16 + lr;                  \
        _Pragma("unroll")                                                      \
        for (int ks_ = 0; ks_ < 2; ++ks_)                                      \
            (dst)[j_][ks_] = *(const short8*)((base) + (row_ << 6) +           \
                              (((ks_ * 4 + lq) ^ (row_ & 7)) << 3));           \
    }                                                                          \
} while (0)

#define MM(hm, hn, bsrc) do {                                                  \
    __builtin_amdgcn_s_setprio(1);                                             \
    _Pragma("unroll")                                                          \
    for (int i_ = 0; i_ < 4; ++i_)                                             \
        _Pragma("unroll")                                                      \
        for (int j_ = 0; j_ < 2; ++j_)                                         \
            _Pragma("unroll")                                                  \
            for (int ks_ = 0; ks_ < 2; ++ks_)                                  \
                acc[(hm) * 4 + i_][(hn) * 2 + j_] =                            \
                    __builtin_amdgcn_mfma_f32_16x16x32_bf16(                   \
                        af[i_][ks_], (bsrc)[j_][ks_],                          \
                        acc[(hm) * 4 + i_][(hn) * 2 + j_], 0, 0, 0);           \
    __builtin_amdgcn_s_setprio(0);                                             \
} while (0)

#define PBAR() do {                                                            \
    __builtin_amdgcn_sched_barrier(0);                                         \
    __builtin_amdgcn_s_barrier();                                              \
    __builtin_amdgcn_sched_barrier(0);                                         \
} while (0)

// One K-tile. STG: stage tile kt+1 and prefetch its b0 (0 for last tile).
#define KTILE(kt, STG) do {                                                    \
    const int p_ = (kt) & 1, q_ = p_ ^ 1;                                      \
    const u16* Ab_ = As[p_];                                                   \
    const u16* Bb_ = Bs[p_];                                                   \
    /* ---- ph1 ---- */                                                        \
    if (STG) { STAGE_A(q_, (kt) + 1, 0); STAGE_B(q_, (kt) + 1, 0); }           \
    READ_A(Ab_, 0);                                                            \
    READ_B(b1, Bb_, 1);                                                        \
    PBAR();                                                                    \
    MM(0, 0, b0);                                                              \
    /* ---- ph2 ---- */                                                        \
    if (STG) { STAGE_B(q_, (kt) + 1, 1); STAGE_A(q_, (kt) + 1, 1); }           \
    PBAR();                                                                    \
    MM(0, 1, b1);                                                              \
    READ_A(Ab_, 1);   /* a1 into af (af0 dead); used next phase */             \
    /* ---- ph3 ---- */                                                        \
    asm volatile("s_waitcnt vmcnt(4)" ::: "memory");                           \
    PBAR();                                                                    \
    MM(1, 0, b0);                                                              \
    /* ---- ph4 ---- */                                                        \
    if (STG) READ_B(b0, Bs[q_], 0);   /* next tile's b0 (region drained ph3) */\
    asm volatile("s_waitcnt vmcnt(0)" ::: "memory");                           \
    PBAR();                                                                    \
    MM(1, 1, b1);                                                              \
} while (0)

__global__ __launch_bounds__(512, 2) void gemm256(
    const u16* __restrict__ A, const u16* __restrict__ BT,
    const float* __restrict__ bias, void* __restrict__ C,
    int ldn, int c_is_f32)
{
    __shared__ __align__(16) u16 As[2][256 * 64];   // 64 KiB
    __shared__ __align__(16) u16 Bs[2][256 * 64];   // 64 KiB

    const int t = threadIdx.x;
    const int w = t >> 6, l = t & 63;
    const int wm = w >> 2, wn = w & 3;              // 2M x 4N wave grid
    const int lr = l & 15, lq = l >> 4;

    // T1: bijective XCD swizzle (nwg = 1152 or 384, both % 8 == 0)
    const int gx = (int)gridDim.x;
    const int nwg = gx * (int)gridDim.y;
    const int lin = (int)blockIdx.y * gx + (int)blockIdx.x;
    const int swz = (lin & 7) * (nwg >> 3) + (lin >> 3);
    const int by = swz / gx, bx = swz - by * gx;
    const int mBase = by * 256, nBase = bx * 256;

    // staging source (pre-swizzled so linear global_load_lds yields
    // LDS[row][c] = global chunk c^(row&7))
    const int srow = t >> 3;                         // 0..63
    const int schk = (t & 7) ^ (srow & 7);           // swizzled 16B chunk
    const u16* aS = A  + (size_t)(mBase + srow) * DIMC + schk * 8;
    const u16* bS = BT + (size_t)(nBase + srow) * DIMC + schk * 8;

    f32x4 acc[8][4];
    #pragma unroll
    for (int i = 0; i < 8; ++i)
        #pragma unroll
        for (int j = 0; j < 4; ++j)
            acc[i][j] = (f32x4){0.f, 0.f, 0.f, 0.f};

    short8 af[4][2], b0[2][2], b1[2][2];

    // prologue: stage tile0 fully into buf0; drain; prefetch b0
    STAGE_A(0, 0, 0); STAGE_B(0, 0, 0); STAGE_B(0, 0, 1); STAGE_A(0, 0, 1);
    asm volatile("s_waitcnt vmcnt(0)" ::: "memory");
    PBAR();
    READ_B(b0, Bs[0], 0);

    #pragma unroll 1
    for (int kt = 0; kt < NKT - 1; ++kt) { KTILE(kt, 1); }
    { KTILE(NKT - 1, 0); }

    // epilogue: C/D layout col=lane&15, row=(lane>>4)*4+reg (m89-verified)
    // acc[hm*4+i][hn*2+j] -> row = mBase + hm*128 + wm*64 + i*16 + lq*4
    //                        col = nBase + hn*128 + wn*32 + j*16 + lr
    #pragma unroll
    for (int hn = 0; hn < 2; ++hn)
        #pragma unroll
        for (int j = 0; j < 2; ++j) {
            const int col = nBase + hn * 128 + wn * 32 + j * 16 + lr;
            const float bb = bias[col];
            #pragma unroll
            for (int hm = 0; hm < 2; ++hm)
                #pragma unroll
                for (int i = 0; i < 4; ++i) {
                    const int row = mBase + hm * 128 + wm * 64 + i * 16 + lq * 4;
                    #pragma unroll
                    for (int rg = 0; rg < 4; ++rg) {
                        float v = acc[hm * 4 + i][hn * 2 + j][rg] + bb;
                        size_t idx = (size_t)(row + rg) * ldn + col;
                        if (c_is_f32) ((float*)C)[idx] = v;
                        else          ((u16*)C)[idx]   = f2b(v);
                    }
                }
        }
}

// ---- head-attention per position (bf16 qkv in, bf16 sum out) ----
__global__ __launch_bounds__(256) void headattn(
    const u16* __restrict__ qkv, u16* __restrict__ sum, int accumulate)
{
    __shared__ float qs[4][12 * 65];
    __shared__ float ks[4][12 * 65];
    __shared__ float vs[4][12 * 65];
    __shared__ float Sld[4][144];
    const int t = threadIdx.x, wv = t >> 6, lane = t & 63;
    const int p = blockIdx.x * 4 + wv;
    const u16* row = qkv + (size_t)p * NQKV;

    #pragma unroll
    for (int j = 0; j < 9; ++j) {
        int u2 = lane + 64 * j;
        uint2 d2 = *(const uint2*)(row + u2 * 4);
        int c = u2 * 4;
        int s = c / 768, rr = c % 768;
        int h = rr >> 6, d = rr & 63;
        float* dst = (s == 0) ? qs[wv] : (s == 1) ? ks[wv] : vs[wv];
        dst[h * 65 + d + 0] = b2f((u16)(d2.x & 0xffffu));
        dst[h * 65 + d + 1] = b2f((u16)(d2.x >> 16));
        dst[h * 65 + d + 2] = b2f((u16)(d2.y & 0xffffu));
        dst[h * 65 + d + 3] = b2f((u16)(d2.y >> 16));
    }
    __syncthreads();
    for (int e = lane; e < 144; e += 64) {
        int h = e / 12, g = e - h * 12;
        float s = 0.f;
        #pragma unroll 8
        for (int d = 0; d < 64; ++d)
            s = fmaf(qs[wv][h * 65 + d], ks[wv][g * 65 + d], s);
        Sld[wv][e] = s * 0.125f;
    }
    __syncthreads();
    if (lane < 12) {
        float m = -1e30f;
        #pragma unroll
        for (int g = 0; g < 12; ++g) m = fmaxf(m, Sld[wv][lane * 12 + g]);
        float ex[12]; float ssum = 0.f;
        #pragma unroll
        for (int g = 0; g < 12; ++g) { ex[g] = __expf(Sld[wv][lane * 12 + g] - m); ssum += ex[g]; }
        float inv = 1.f / ssum;
        #pragma unroll
        for (int g = 0; g < 12; ++g) Sld[wv][lane * 12 + g] = ex[g] * inv;
    }
    __syncthreads();
    u16* orow = sum + (size_t)p * DIMC;
    #pragma unroll
    for (int h = 0; h < 12; ++h) {
        float o = 0.f;
        #pragma unroll
        for (int g = 0; g < 12; ++g)
            o = fmaf(Sld[wv][h * 12 + g], vs[wv][g * 65 + lane], o);
        int idx = h * 64 + lane;
        if (accumulate) o += b2f(orow[idx]);
        orow[idx] = f2b(o);
    }
}

extern "C" void kernel_launch(void* const* d_in, const int* in_sizes, int n_in,
                              void* d_out, int out_size, void* d_ws, size_t ws_size,
                              hipStream_t stream) {
    const float* x  = (const float*)d_in[0];
    const float* wh = (const float*)d_in[1];
    const float* bh = (const float*)d_in[2];
    const float* ww = (const float*)d_in[3];
    const float* bw = (const float*)d_in[4];
    const float* wp = (const float*)d_in[5];
    const float* bp = (const float*)d_in[6];
    float* out = (float*)d_out;

    // ws (u16 elems): xb 25165824 | whT 1769472 | wwT 1769472 | wpT 589824 |
    //                 qkv 75497472 | sumb 25165824   => ~260 MB
    u16* xb   = (u16*)d_ws;
    u16* whT  = xb   + 25165824;
    u16* wwT  = whT  + 1769472;
    u16* wpT  = wwT  + 1769472;
    u16* qkvb = wpT  + 589824;
    u16* sumb = qkvb + 75497472;

    cvt_bf16<<<24576, 256, 0, stream>>>(x, xb, 6291456);
    dim3 wg(36, 12, 3);
    cvt_wT<<<wg, 256, 0, stream>>>(wh, ww, wp, whT, wwT, wpT);

    dim3 gq(NQKV / 256, NPOS / 256);      // (9, 128)  -> 1152 blocks
    dim3 gp(DIMC / 256, NPOS / 256);      // (3, 128)  ->  384 blocks

    gemm256<<<gq, 512, 0, stream>>>(xb, whT, bh, qkvb, NQKV, 0);
    headattn<<<NPOS / 4, 256, 0, stream>>>(qkvb, sumb, 0);
    gemm256<<<gq, 512, 0, stream>>>(xb, wwT, bw, qkvb, NQKV, 0);
    headattn<<<NPOS / 4, 256, 0, stream>>>(qkvb, sumb, 1);
    gemm256<<<gp, 512, 0, stream>>>(sumb, wpT, bp, out, DIMC, 1);
}

// Round 3
// 585.145 us; speedup vs baseline: 1.3494x; 1.2435x over previous
//
#include <hip/hip_runtime.h>

typedef unsigned short u16;
typedef unsigned int u32;
typedef __attribute__((ext_vector_type(8))) short short8;
typedef __attribute__((ext_vector_type(4))) float f32x4;

#define DIMC 768
#define NQKV 2304
#define NPOS 32768
#define NKT 12   // 768 / 64

__device__ __forceinline__ float b2f(u16 u) {
    union { u32 i; float f; } c; c.i = ((u32)u) << 16; return c.f;
}
__device__ __forceinline__ u16 f2b(float f) {
    union { float f; u32 i; } c; c.f = f;
    u32 r = c.i + 0x7fffu + ((c.i >> 16) & 1u);
    return (u16)(r >> 16);
}

// async global->LDS, 16B per lane; lds dst is wave-uniform base + lane*16
__device__ __forceinline__ void gl_lds16(const void* g, void* l) {
    __builtin_amdgcn_global_load_lds(
        (const __attribute__((address_space(1))) void*)g,
        (__attribute__((address_space(3))) void*)l, 16, 0, 0);
}

// ---- fp32 -> bf16 elementwise (x) ----
__global__ __launch_bounds__(256) void cvt_bf16(
    const float* __restrict__ in, u16* __restrict__ out, int n4)
{
    int i = blockIdx.x * 256 + threadIdx.x;
    if (i >= n4) return;
    float4 v = ((const float4*)in)[i];
    ushort4 o;
    o.x = f2b(v.x); o.y = f2b(v.y); o.z = f2b(v.z); o.w = f2b(v.w);
    ((ushort4*)out)[i] = o;
}

// ---- fp32 W[768][N] -> bf16 WT[N][768] (transpose + convert), 64x64 tiles ----
__global__ __launch_bounds__(256) void cvt_wT(
    const float* __restrict__ W0, const float* __restrict__ W1,
    const float* __restrict__ W2,
    u16* __restrict__ T0, u16* __restrict__ T1, u16* __restrict__ T2)
{
    const int z = blockIdx.z;
    const float* W = (z == 0) ? W0 : (z == 1) ? W1 : W2;
    u16* WT = (z == 0) ? T0 : (z == 1) ? T1 : T2;
    const int N = (z == 2) ? 768 : 2304;
    const int nb = blockIdx.x, kb = blockIdx.y;
    if (nb * 64 >= N) return;                       // block-uniform
    __shared__ u16 T[64][65];
    const int t = threadIdx.x, sr = t >> 2, sc = t & 3;
    {
        const float4* p = (const float4*)(W + (size_t)(kb * 64 + sr) * N + nb * 64 + sc * 16);
        float4 a0 = p[0], a1 = p[1], a2 = p[2], a3 = p[3];
        float vv[16] = {a0.x, a0.y, a0.z, a0.w, a1.x, a1.y, a1.z, a1.w,
                        a2.x, a2.y, a2.z, a2.w, a3.x, a3.y, a3.z, a3.w};
        #pragma unroll
        for (int i = 0; i < 16; ++i)
            T[sc * 16 + i][sr] = f2b(vv[i]);
    }
    __syncthreads();
    {
        u16 vv[16];
        #pragma unroll
        for (int i = 0; i < 16; ++i) vv[i] = T[sr][sc * 16 + i];
        uint4 p0, p1;
        p0.x = vv[0] | ((u32)vv[1] << 16);  p0.y = vv[2] | ((u32)vv[3] << 16);
        p0.z = vv[4] | ((u32)vv[5] << 16);  p0.w = vv[6] | ((u32)vv[7] << 16);
        p1.x = vv[8] | ((u32)vv[9] << 16);  p1.y = vv[10] | ((u32)vv[11] << 16);
        p1.z = vv[12] | ((u32)vv[13] << 16); p1.w = vv[14] | ((u32)vv[15] << 16);
        u16* q = WT + (size_t)(nb * 64 + sr) * DIMC + kb * 64 + sc * 16;
        *(uint4*)q = p0;
        *(uint4*)(q + 8) = p1;
    }
}

// ============================================================================
// 256x256 MFMA GEMM, 4 phases / 4 barriers per K-tile, deep staging pipeline.
// 512 threads = 8 waves (2M x 4N); per-wave output 128x64; BK=64.
// LDS 128 KiB: 2 dbuf x ([256][64] A + [256][64] B), XOR-swizzled (T2).
//
// Stage slots (tile T, all 2 x gl_lds16 each):
//   P1: B1(T+1)->q   P2: A1(T+1)->q   P3: A0(T+2)->p   P4: B0(T+2)->p
// Reads (tile T from p): P1: af0(8)+b0(4); P2: b1(4); P3: af1(8); P4: none.
// Quadrants: P1 MM(0,0)  P2 MM(0,1)  P3 MM(1,0)  P4 MM(1,1).
// Region safety: each stage's target region last-read >=2 barriers earlier.
// Single counted vmcnt(4) at P4 (before the barrier) waits exactly tile
// T+1's four halves (issued 2..5 phases earlier); leaves T+2's A0,B0 (4
// instrs) in flight. vmcnt always precedes a barrier -> cross-wave sound.
// ============================================================================

#define STAGE_A(buf, kt, ht) do {                                              \
    gl_lds16(aS + (size_t)((ht) * 128)      * DIMC + (size_t)(kt) * 64,        \
             &As[buf][(ht) * 8192 +        w * 512]);                          \
    gl_lds16(aS + (size_t)((ht) * 128 + 64) * DIMC + (size_t)(kt) * 64,        \
             &As[buf][(ht) * 8192 + 4096 + w * 512]);                          \
} while (0)

#define STAGE_B(buf, kt, ht) do {                                              \
    gl_lds16(bS + (size_t)((ht) * 128)      * DIMC + (size_t)(kt) * 64,        \
             &Bs[buf][(ht) * 8192 +        w * 512]);                          \
    gl_lds16(bS + (size_t)((ht) * 128 + 64) * DIMC + (size_t)(kt) * 64,        \
             &Bs[buf][(ht) * 8192 + 4096 + w * 512]);                          \
} while (0)

// read A half hm (rows hm*128 + wm*64 + i*16 + lr) into af
#define READ_A(base, hm) do {                                                  \
    _Pragma("unroll")                                                          \
    for (int i_ = 0; i_ < 4; ++i_) {                                           \
        const int row_ = (hm) * 128 + wm * 64 + i_ * 16 + lr;                  \
        _Pragma("unroll")                                                      \
        for (int ks_ = 0; ks_ < 2; ++ks_)                                      \
            af[i_][ks_] = *(const short8*)((base) + (row_ << 6) +              \
                              (((ks_ * 4 + lq) ^ (row_ & 7)) << 3));           \
    }                                                                          \
} while (0)

// read B half hn (rows hn*128 + wn*32 + j*16 + lr) into dst
#define READ_B(dst, base, hn) do {                                             \
    _Pragma("unroll")                                                          \
    for (int j_ = 0; j_ < 2; ++j_) {                                           \
        const int row_ = (hn) * 128 + wn * 32 + j_ * 16 + lr;                  \
        _Pragma("unroll")                                                      \
        for (int ks_ = 0; ks_ < 2; ++ks_)                                      \
            (dst)[j_][ks_] = *(const short8*)((base) + (row_ << 6) +           \
                              (((ks_ * 4 + lq) ^ (row_ & 7)) << 3));           \
    }                                                                          \
} while (0)

#define MM(hm, hn, bsrc) do {                                                  \
    __builtin_amdgcn_s_setprio(1);                                             \
    _Pragma("unroll")                                                          \
    for (int i_ = 0; i_ < 4; ++i_)                                             \
        _Pragma("unroll")                                                      \
        for (int j_ = 0; j_ < 2; ++j_)                                         \
            _Pragma("unroll")                                                  \
            for (int ks_ = 0; ks_ < 2; ++ks_)                                  \
                acc[(hm) * 4 + i_][(hn) * 2 + j_] =                            \
                    __builtin_amdgcn_mfma_f32_16x16x32_bf16(                   \
                        af[i_][ks_], (bsrc)[j_][ks_],                          \
                        acc[(hm) * 4 + i_][(hn) * 2 + j_], 0, 0, 0);           \
    __builtin_amdgcn_s_setprio(0);                                             \
} while (0)

#define BAR() do {                                                             \
    __builtin_amdgcn_sched_barrier(0);                                         \
    __builtin_amdgcn_s_barrier();                                              \
    __builtin_amdgcn_sched_barrier(0);                                         \
} while (0)

// One K-tile. S12: stage tile kt+1 halves B1/A1. S34: stage tile kt+2 A0/B0.
#define KTILE(kt, S12, S34, VN) do {                                           \
    const int p_ = (kt) & 1, q_ = p_ ^ 1;                                      \
    const u16* Ab_ = As[p_];                                                   \
    const u16* Bb_ = Bs[p_];                                                   \
    /* ---- P1 ---- */                                                         \
    READ_A(Ab_, 0);                                                            \
    READ_B(b0, Bb_, 0);                                                        \
    if (S12) STAGE_B(q_, (kt) + 1, 1);                                         \
    BAR();                                                                     \
    MM(0, 0, b0);                                                              \
    /* ---- P2 ---- */                                                         \
    READ_B(b1, Bb_, 1);                                                        \
    if (S12) STAGE_A(q_, (kt) + 1, 1);                                         \
    BAR();                                                                     \
    MM(0, 1, b1);                                                              \
    /* ---- P3 ---- */                                                         \
    READ_A(Ab_, 1);                                                            \
    if (S34) STAGE_A(p_, (kt) + 2, 0);                                         \
    BAR();                                                                     \
    MM(1, 0, b0);                                                              \
    /* ---- P4 ---- */                                                         \
    if (S34) STAGE_B(p_, (kt) + 2, 0);                                         \
    __builtin_amdgcn_sched_barrier(0);                                         \
    asm volatile("s_waitcnt vmcnt(" VN ")" ::: "memory");                      \
    BAR();                                                                     \
    MM(1, 1, b1);                                                              \
} while (0)

__global__ __launch_bounds__(512, 2) void gemm256(
    const u16* __restrict__ A, const u16* __restrict__ BT,
    const float* __restrict__ bias, void* __restrict__ C,
    int ldn, int c_is_f32)
{
    __shared__ __align__(16) u16 As[2][256 * 64];   // 64 KiB
    __shared__ __align__(16) u16 Bs[2][256 * 64];   // 64 KiB

    const int t = threadIdx.x;
    const int w = t >> 6, l = t & 63;
    const int wm = w >> 2, wn = w & 3;              // 2M x 4N wave grid
    const int lr = l & 15, lq = l >> 4;

    // T1: bijective XCD swizzle (nwg = 1152 or 384, both % 8 == 0)
    const int gx = (int)gridDim.x;
    const int nwg = gx * (int)gridDim.y;
    const int lin = (int)blockIdx.y * gx + (int)blockIdx.x;
    const int swz = (lin & 7) * (nwg >> 3) + (lin >> 3);
    const int by = swz / gx, bx = swz - by * gx;
    const int mBase = by * 256, nBase = bx * 256;

    // staging source (pre-swizzled so linear global_load_lds yields
    // LDS[row][c] = global chunk c^(row&7))
    const int srow = t >> 3;                         // 0..63
    const int schk = (t & 7) ^ (srow & 7);           // swizzled 16B chunk
    const u16* aS = A  + (size_t)(mBase + srow) * DIMC + schk * 8;
    const u16* bS = BT + (size_t)(nBase + srow) * DIMC + schk * 8;

    f32x4 acc[8][4];
    #pragma unroll
    for (int i = 0; i < 8; ++i)
        #pragma unroll
        for (int j = 0; j < 4; ++j)
            acc[i][j] = (f32x4){0.f, 0.f, 0.f, 0.f};

    short8 af[4][2], b0[2][2], b1[2][2];

    // prologue: tile0 all 4 halves (buf0) + tile1 A0,B0 (buf1).
    // vmcnt(4) waits tile0's 8 instrs, leaves tile1's 4 in flight.
    STAGE_A(0, 0, 0); STAGE_B(0, 0, 0); STAGE_B(0, 0, 1); STAGE_A(0, 0, 1);
    STAGE_A(1, 1, 0); STAGE_B(1, 1, 0);
    __builtin_amdgcn_sched_barrier(0);
    asm volatile("s_waitcnt vmcnt(4)" ::: "memory");
    BAR();

    #pragma unroll 1
    for (int kt = 0; kt < NKT - 2; ++kt) { KTILE(kt, 1, 1, "4"); }
    { KTILE(NKT - 2, 1, 0, "0"); }
    { KTILE(NKT - 1, 0, 0, "0"); }

    // epilogue: C/D layout col=lane&15, row=(lane>>4)*4+reg (m89-verified)
    #pragma unroll
    for (int hn = 0; hn < 2; ++hn)
        #pragma unroll
        for (int j = 0; j < 2; ++j) {
            const int col = nBase + hn * 128 + wn * 32 + j * 16 + lr;
            const float bb = bias[col];
            #pragma unroll
            for (int hm = 0; hm < 2; ++hm)
                #pragma unroll
                for (int i = 0; i < 4; ++i) {
                    const int row = mBase + hm * 128 + wm * 64 + i * 16 + lq * 4;
                    #pragma unroll
                    for (int rg = 0; rg < 4; ++rg) {
                        float v = acc[hm * 4 + i][hn * 2 + j][rg] + bb;
                        size_t idx = (size_t)(row + rg) * ldn + col;
                        if (c_is_f32) ((float*)C)[idx] = v;
                        else          ((u16*)C)[idx]   = f2b(v);
                    }
                }
        }
}

// ============================================================================
// head-attention via MFMA: one wave per position, 4 waves/block.
// qkv row = [q(12x64)|k(12x64)|v(12x64)] bf16.
// S = (Q K^T)*0.125 via 2x mfma_16x16x32 (frags loaded DIRECT from global:
//   A: lane holds Q[l&15][lq*8..+8], B: lane holds K[l&15][lq*8..+8]).
// Softmax over g: wave-parallel shfl_xor reduce within 16-lane groups.
// P (bf16) and V^T bounce through per-wave LDS; PV via 4x mfma (d-chunks).
// k=12..31 contributions killed by explicit zeros (P cols >=12 = 0, Vt cols
// 12..15 zeroed, k>=16 frags zeroed in registers) -> no 0*garbage NaN.
// ============================================================================
__global__ __launch_bounds__(256) void headattn(
    const u16* __restrict__ qkv, u16* __restrict__ sum, int accumulate)
{
    __shared__ u16 VtL[4][64 * 16];   // per-wave V^T: Vt[d][g], g padded to 16
    __shared__ u16 PL[4][16 * 16];    // per-wave P[h][g]
    const int t = threadIdx.x, wv = t >> 6, l = t & 63;
    const int p = blockIdx.x * 4 + wv;
    const u16* row = qkv + (size_t)p * NQKV;
    const int lr = l & 15, lq = l >> 4;
    u16* Vt = VtL[wv];
    u16* P  = PL[wv];

    // Q/K fragments straight from global (rows >=12 read neighbor region:
    // finite garbage, masked later)
    short8 qa0 = *(const short8*)(row +       lr * 64 + lq * 8);
    short8 qa1 = *(const short8*)(row +       lr * 64 + lq * 8 + 32);
    short8 kb0 = *(const short8*)(row + 768 + lr * 64 + lq * 8);
    short8 kb1 = *(const short8*)(row + 768 + lr * 64 + lq * 8 + 32);

    // stage V^T: Vt[d][g] = V[g][d]; zero-pad g=12..15 (lane l owns row d=l)
    *(uint2*)(Vt + l * 16 + 12) = (uint2){0u, 0u};
    {
        const int g = l >> 3, d0 = (l & 7) * 8;
        short8 v = *(const short8*)(row + 1536 + g * 64 + d0);
        #pragma unroll
        for (int i = 0; i < 8; ++i) Vt[(d0 + i) * 16 + g] = (u16)v[i];
        if (l < 32) {
            const int g2 = 8 + (l >> 3);
            short8 v2 = *(const short8*)(row + 1536 + g2 * 64 + d0);
            #pragma unroll
            for (int i = 0; i < 8; ++i) Vt[(d0 + i) * 16 + g2] = (u16)v2[i];
        }
    }

    // S = Q K^T (C layout: S[h=lq*4+rg][g=lr])
    f32x4 s = (f32x4){0.f, 0.f, 0.f, 0.f};
    s = __builtin_amdgcn_mfma_f32_16x16x32_bf16(qa0, kb0, s, 0, 0, 0);
    s = __builtin_amdgcn_mfma_f32_16x16x32_bf16(qa1, kb1, s, 0, 0, 0);

    // softmax over g (16-lane groups share one h-row per rg)
    #pragma unroll
    for (int rg = 0; rg < 4; ++rg) {
        float x = (lr < 12) ? s[rg] * 0.125f : -1e30f;
        float m = x;
        m = fmaxf(m, __shfl_xor(m, 1));
        m = fmaxf(m, __shfl_xor(m, 2));
        m = fmaxf(m, __shfl_xor(m, 4));
        m = fmaxf(m, __shfl_xor(m, 8));
        float e = (lr < 12) ? __expf(x - m) : 0.f;
        float ss = e;
        ss += __shfl_xor(ss, 1);
        ss += __shfl_xor(ss, 2);
        ss += __shfl_xor(ss, 4);
        ss += __shfl_xor(ss, 8);
        P[(lq * 4 + rg) * 16 + lr] = f2b(e / ss);
    }

    // PV: O[h][d] = P(16x16,zeropad k>=16) x Vt-as-B (4 d-chunks of 16)
    const short8 z8 = (short8){0, 0, 0, 0, 0, 0, 0, 0};
    short8 pa = z8;
    if (lq < 2) pa = *(const short8*)(P + lr * 16 + lq * 8);
    f32x4 o[4];
    #pragma unroll
    for (int c = 0; c < 4; ++c) {
        short8 vb = z8;
        if (lq < 2) vb = *(const short8*)(Vt + (c * 16 + lr) * 16 + lq * 8);
        f32x4 a0 = (f32x4){0.f, 0.f, 0.f, 0.f};
        o[c] = __builtin_amdgcn_mfma_f32_16x16x32_bf16(pa, vb, a0, 0, 0, 0);
    }

    // store rows h<12 (lq groups 0..2)
    if (lq < 3) {
        u16* orow = sum + (size_t)p * DIMC;
        #pragma unroll
        for (int c = 0; c < 4; ++c)
            #pragma unroll
            for (int rg = 0; rg < 4; ++rg) {
                const int idx = (lq * 4 + rg) * 64 + c * 16 + lr;
                float v = o[c][rg];
                if (accumulate) v += b2f(orow[idx]);
                orow[idx] = f2b(v);
            }
    }
}

extern "C" void kernel_launch(void* const* d_in, const int* in_sizes, int n_in,
                              void* d_out, int out_size, void* d_ws, size_t ws_size,
                              hipStream_t stream) {
    const float* x  = (const float*)d_in[0];
    const float* wh = (const float*)d_in[1];
    const float* bh = (const float*)d_in[2];
    const float* ww = (const float*)d_in[3];
    const float* bw = (const float*)d_in[4];
    const float* wp = (const float*)d_in[5];
    const float* bp = (const float*)d_in[6];
    float* out = (float*)d_out;

    // ws (u16 elems): xb 25165824 | whT 1769472 | wwT 1769472 | wpT 589824 |
    //                 qkv 75497472 | sumb 25165824   => ~260 MB
    u16* xb   = (u16*)d_ws;
    u16* whT  = xb   + 25165824;
    u16* wwT  = whT  + 1769472;
    u16* wpT  = wwT  + 1769472;
    u16* qkvb = wpT  + 589824;
    u16* sumb = qkvb + 75497472;

    cvt_bf16<<<24576, 256, 0, stream>>>(x, xb, 6291456);
    dim3 wg(36, 12, 3);
    cvt_wT<<<wg, 256, 0, stream>>>(wh, ww, wp, whT, wwT, wpT);

    dim3 gq(NQKV / 256, NPOS / 256);      // (9, 128)  -> 1152 blocks
    dim3 gp(DIMC / 256, NPOS / 256);      // (3, 128)  ->  384 blocks

    gemm256<<<gq, 512, 0, stream>>>(xb, whT, bh, qkvb, NQKV, 0);
    headattn<<<NPOS / 4, 256, 0, stream>>>(qkvb, sumb, 0);
    gemm256<<<gq, 512, 0, stream>>>(xb, wwT, bw, qkvb, NQKV, 0);
    headattn<<<NPOS / 4, 256, 0, stream>>>(qkvb, sumb, 1);
    gemm256<<<gp, 512, 0, stream>>>(sumb, wpT, bp, out, DIMC, 1);
}